// Round 5
// baseline (153.219 us; speedup 1.0000x reference)
//
#include <hip/hip_runtime.h>
#include <math.h>

// Problem constants (fixed by setup_inputs)
constexpr int Bc  = 32768;
constexpr int NAc = 60;
constexpr int NRc = 4;

constexpr int NP        = Bc * NAc;        // 1,966,080 pairs
constexpr int TILE      = 256;             // pairs per tile
constexpr int TPA       = 2;               // tiles per A-block
constexpr int PAIRS_PB  = TILE * TPA;      // 512 pairs / A-block
constexpr int A_BLOCKS  = NP / PAIRS_PB;   // 3840 (exact)
constexpr int B_BLOCKS  = Bc / 4;          // 8192: 4 waves/block, 1 b/wave
constexpr int TOT_BLOCKS = A_BLOCKS + B_BLOCKS;

// cos(1.0 rad): mask (gt_bias < 1) <=> clip(0.5*(tr-1)) > cos(1)
#define COS_ONE 0.5403023058681398f

// async global->LDS, 16B per lane; LDS dest must be wave-uniform base + lane*16
// (our mapping is the exact identity copy, so it is).
__device__ __forceinline__ void async_ld16(const float* g, float* l) {
    __builtin_amdgcn_global_load_lds(
        (const __attribute__((address_space(1))) void*)g,
        (__attribute__((address_space(3))) void*)l, 16, 0, 0);
}

__global__ __launch_bounds__(256) void mtl_fused(
    const float* __restrict__ wts,      // (B, NA)
    const int*   __restrict__ label,    // (B,)
    const float* __restrict__ y,        // (B, NR, NA)
    const float* __restrict__ gt_R,     // (B, NA, 9)
    const float* __restrict__ anchors,  // (NA, 9)
    float*       __restrict__ out,      // [.., ang_err at 4+b]
    float*       __restrict__ l2p,      // (A_BLOCKS,)
    float*       __restrict__ lpp,      // (B_BLOCKS,)
    float*       __restrict__ crp)      // (B_BLOCKS,)
{
    __shared__ __align__(16) float smem[PAIRS_PB * 9 + 16];   // 18496 B
    const int tid  = threadIdx.x;
    const int lane = tid & 63;
    const int wave = tid >> 6;

    if (blockIdx.x < A_BLOCKS) {
        // ============ phase A: masked Frobenius l2, 512 pairs ============
        float* sg = smem;   // 4608 floats
        const float* gbase = gt_R + (size_t)blockIdx.x * (PAIRS_PB * 9);

        // async-stage 18 chunks of 1KB (identity copy), 4-5 per wave
        for (int c = wave; c < 18; c += 4)
            async_ld16(gbase + c * 256 + lane * 4, sg + c * 256 + lane * 4);

        // y quaternion prefetch into registers (independent of LDS)
        float qw[TPA], qx[TPA], qy[TPA], qz[TPA];
        #pragma unroll
        for (int t = 0; t < TPA; ++t) {
            int p = blockIdx.x * PAIRS_PB + t * TILE + tid;
            int b = p / NAc;
            int a = p - b * NAc;
            const float* yb = y + (size_t)b * (NRc * NAc) + a;
            qw[t] = yb[0 * NAc];
            qx[t] = yb[1 * NAc];
            qy[t] = yb[2 * NAc];
            qz[t] = yb[3 * NAc];
        }
        __syncthreads();   // drains async staging + register loads

        float acc = 0.0f;
        #pragma unroll
        for (int t = 0; t < TPA; ++t) {
            const float* g = sg + t * (TILE * 9) + tid * 9;  // 2-way bank alias: free
            float g0 = g[0], g1 = g[1], g2 = g[2];
            float g3 = g[3], g4 = g[4], g5 = g[5];
            float g6 = g[6], g7 = g[7], g8 = g[8];

            float n   = sqrtf(qw[t]*qw[t] + qx[t]*qx[t] + qy[t]*qy[t] + qz[t]*qz[t]);
            float inv = 1.0f / fmaxf(n, 1e-8f);
            float w = qw[t] * inv, x = qx[t] * inv, yq = qy[t] * inv, z = qz[t] * inv;

            float R00 = 1.0f - 2.0f * (yq * yq + z * z);
            float R01 = 2.0f * (x * yq - z * w);
            float R02 = 2.0f * (x * z + yq * w);
            float R10 = 2.0f * (x * yq + z * w);
            float R11 = 1.0f - 2.0f * (x * x + z * z);
            float R12 = 2.0f * (yq * z - x * w);
            float R20 = 2.0f * (x * z - yq * w);
            float R21 = 2.0f * (yq * z + x * w);
            float R22 = 1.0f - 2.0f * (x * x + yq * yq);

            float xb = 0.5f * (g0 + g4 + g8 - 1.0f);
            if (xb > COS_ONE) {
                float d0 = g0 - R00, d1 = g1 - R01, d2 = g2 - R02;
                float d3 = g3 - R10, d4 = g4 - R11, d5 = g5 - R12;
                float d6 = g6 - R20, d7 = g7 - R21, d8 = g8 - R22;
                acc += d0*d0 + d1*d1 + d2*d2
                     + d3*d3 + d4*d4 + d5*d5
                     + d6*d6 + d7*d7 + d8*d8;
            }
        }

        for (int off = 32; off; off >>= 1) acc += __shfl_xor(acc, off, 64);
        float* sred = smem + PAIRS_PB * 9;   // 4 floats, past sg
        if (lane == 0) sred[wave] = acc;
        __syncthreads();
        if (tid == 0) l2p[blockIdx.x] = sred[0] + sred[1] + sred[2] + sred[3];

    } else {
        // ============ phase B: cls / r_acc / ang_err, 1 b per wave ============
        const int cb = blockIdx.x - A_BLOCKS;
        const int b  = cb * 4 + wave;
        float* sA   = smem;        // 540 floats: anchors
        float* s_lp = smem + 544;  // 4
        float* s_cr = smem + 548;  // 4

        // issue all independent loads up front
        float w = -INFINITY;
        if (lane < NAc) w = wts[(size_t)b * NAc + lane];
        int lab = label[b];

        // true_R row (wave-uniform address) — prefetch before argmax
        const float* tRp = gt_R + ((size_t)b * NAc + 29) * 9;
        float t0 = tRp[0], t1 = tRp[1], t2 = tRp[2];
        float t3 = tRp[3], t4 = tRp[4], t5 = tRp[5];
        float t6 = tRp[6], t7 = tRp[7], t8 = tRp[8];

        // speculative per-lane rotmat (removes post-argmax y gather)
        float R00=0,R01=0,R02=0,R10=0,R11=0,R12=0,R20=0,R21=0,R22=0;
        if (lane < NAc) {
            const float* yb = y + (size_t)b * (NRc * NAc) + lane;
            float qw = yb[0 * NAc];
            float qx = yb[1 * NAc];
            float qy = yb[2 * NAc];
            float qz = yb[3 * NAc];
            float n   = sqrtf(qw*qw + qx*qx + qy*qy + qz*qz);
            float inv = 1.0f / fmaxf(n, 1e-8f);
            qw *= inv; qx *= inv; qy *= inv; qz *= inv;
            R00 = 1.0f - 2.0f * (qy*qy + qz*qz);
            R01 = 2.0f * (qx*qy - qz*qw);
            R02 = 2.0f * (qx*qz + qy*qw);
            R10 = 2.0f * (qx*qy + qz*qw);
            R11 = 1.0f - 2.0f * (qx*qx + qz*qz);
            R12 = 2.0f * (qy*qz - qx*qw);
            R20 = 2.0f * (qx*qz - qy*qw);
            R21 = 2.0f * (qy*qz + qx*qw);
            R22 = 1.0f - 2.0f * (qx*qx + qy*qy);
        }

        // stage all anchors to LDS once per block (coalesced)
        for (int i = tid; i < NAc * 9; i += 256) sA[i] = anchors[i];
        __syncthreads();

        // argmax (first-index tie-break) + logsumexp
        float mv = w;
        int   mi = lane;
        for (int off = 32; off; off >>= 1) {
            float ov = __shfl_xor(mv, off, 64);
            int   oi = __shfl_xor(mi, off, 64);
            if (ov > mv || (ov == mv && oi < mi)) { mv = ov; mi = oi; }
        }
        float e  = (lane < NAc) ? expf(w - mv) : 0.0f;
        float se = e;
        for (int off = 32; off; off >>= 1) se += __shfl_xor(se, off, 64);
        float lse  = mv + logf(se);
        float wlab = __shfl(w, lab, 64);

        if (lane == 0) {
            s_lp[wave] = wlab - lse;
            s_cr[wave] = (mi == lab) ? 1.0f : 0.0f;
        }

        if (lane == mi) {
            const float* A = sA + mi * 9;
            float a0 = A[0], a1 = A[1], a2 = A[2];
            float a3 = A[3], a4 = A[4], a5 = A[5];
            float a6 = A[6], a7 = A[7], a8 = A[8];
            float P00 = a0*R00 + a1*R10 + a2*R20;
            float P01 = a0*R01 + a1*R11 + a2*R21;
            float P02 = a0*R02 + a1*R12 + a2*R22;
            float P10 = a3*R00 + a4*R10 + a5*R20;
            float P11 = a3*R01 + a4*R11 + a5*R21;
            float P12 = a3*R02 + a4*R12 + a5*R22;
            float P20 = a6*R00 + a7*R10 + a8*R20;
            float P21 = a6*R01 + a7*R11 + a8*R21;
            float P22 = a6*R02 + a7*R12 + a8*R22;
            float tr = P00*t0 + P01*t1 + P02*t2
                     + P10*t3 + P11*t4 + P12*t5
                     + P20*t6 + P21*t7 + P22*t8;
            float cx = 0.5f * (tr - 1.0f);
            cx = fminf(fmaxf(cx, -1.0f + 1e-7f), 1.0f - 1e-7f);
            out[4 + b] = acosf(cx);
        }

        __syncthreads();
        if (tid == 0) {
            lpp[cb] = s_lp[0] + s_lp[1] + s_lp[2] + s_lp[3];
            crp[cb] = s_cr[0] + s_cr[1] + s_cr[2] + s_cr[3];
        }
    }
}

// ---------------------------------------------------------------------------
// Finalize: 256 threads, float4 strided loads, per-thread double accumulation,
// deterministic shfl+LDS tree.
// ---------------------------------------------------------------------------
__global__ __launch_bounds__(256) void mtl_final(
    const float* __restrict__ l2p,
    const float* __restrict__ lpp,
    const float* __restrict__ crp,
    float*       __restrict__ out)
{
    const int tid  = threadIdx.x;
    const int lane = tid & 63;
    const int wave = tid >> 6;

    double l2 = 0.0, lp = 0.0, cr = 0.0;

    const float4* l2p4 = (const float4*)l2p;   // 3840/4 = 960
    const float4* lpp4 = (const float4*)lpp;   // 8192/4 = 2048
    const float4* crp4 = (const float4*)crp;   // 8192/4 = 2048
    for (int i = tid; i < A_BLOCKS / 4; i += 256) {
        float4 v = l2p4[i];
        l2 += (double)v.x + (double)v.y + (double)v.z + (double)v.w;
    }
    for (int i = tid; i < B_BLOCKS / 4; i += 256) {
        float4 v = lpp4[i];
        lp += (double)v.x + (double)v.y + (double)v.z + (double)v.w;
        float4 u = crp4[i];
        cr += (double)u.x + (double)u.y + (double)u.z + (double)u.w;
    }

    for (int off = 32; off; off >>= 1) {
        l2 += __shfl_xor(l2, off, 64);
        lp += __shfl_xor(lp, off, 64);
        cr += __shfl_xor(cr, off, 64);
    }
    __shared__ double s_l2[4], s_lp[4], s_cr[4];
    if (lane == 0) { s_l2[wave] = l2; s_lp[wave] = lp; s_cr[wave] = cr; }
    __syncthreads();
    if (tid == 0) {
        double t2 = s_l2[0] + s_l2[1] + s_l2[2] + s_l2[3];
        double tp = s_lp[0] + s_lp[1] + s_lp[2] + s_lp[3];
        double tc = s_cr[0] + s_cr[1] + s_cr[2] + s_cr[3];
        float cls = (float)(-tp / (double)Bc);
        float l2s = (float)(10.0 * t2);      // W_LOSS * l2_loss
        out[0] = cls + l2s;                  // loss
        out[1] = cls;                        // cls_loss
        out[2] = l2s;                        // W_LOSS * l2_loss
        out[3] = (float)(tc / (double)Bc);   // r_acc
    }
}

extern "C" void kernel_launch(void* const* d_in, const int* in_sizes, int n_in,
                              void* d_out, int out_size, void* d_ws, size_t ws_size,
                              hipStream_t stream) {
    const float* wts     = (const float*)d_in[0];
    const int*   label   = (const int*)d_in[1];
    const float* y       = (const float*)d_in[2];
    const float* gt_R    = (const float*)d_in[3];
    const float* anchors = (const float*)d_in[4];
    float* out = (float*)d_out;

    float* l2p = (float*)d_ws;           // A_BLOCKS floats
    float* lpp = l2p + A_BLOCKS;         // B_BLOCKS floats
    float* crp = lpp + B_BLOCKS;         // B_BLOCKS floats

    mtl_fused<<<TOT_BLOCKS, 256, 0, stream>>>(wts, label, y, gt_R, anchors,
                                              out, l2p, lpp, crp);
    mtl_final<<<1, 256, 0, stream>>>(l2p, lpp, crp, out);
}

// Round 7
// 139.963 us; speedup vs baseline: 1.0947x; 1.0947x over previous
//
#include <hip/hip_runtime.h>
#include <math.h>

// Problem constants (fixed by setup_inputs)
constexpr int Bc  = 32768;
constexpr int NAc = 60;

constexpr int BPB  = 4;            // batch elems per block (1 per wave)
constexpr int NBLK = Bc / BPB;     // 8192 blocks
constexpr int ROWF = NAc * 9;      // 540 floats of gt_R per b
constexpr int STG4 = BPB * ROWF / 4;  // 540 float4 to stage per block

// cos(1.0 rad): mask (gt_bias < 1) <=> clip(0.5*(tr-1)) > cos(1)
#define COS_ONE 0.5403023058681398f

// ---------------------------------------------------------------------------
// Fully fused: each wave owns one batch element b.
//   lane a<60: pair (b,a) -> rotmat (used for BOTH l2 and ang_err)
//   gt_R rows for the block's 4 b staged via coalesced float4 -> LDS
//   true_R = gt_R[b,29] read from the SAME LDS tile (no extra global load)
//   anchors row a loaded speculatively pre-argmax (L2-hot, 2 KB total)
// ---------------------------------------------------------------------------
__global__ __launch_bounds__(256) void mtl_all(
    const float* __restrict__ wts,      // (B, NA)
    const int*   __restrict__ label,    // (B,)
    const float* __restrict__ y,        // (B, 4, NA)
    const float* __restrict__ gt_R,     // (B, NA, 9)
    const float* __restrict__ anchors,  // (NA, 9)
    float*       __restrict__ out,      // [.., ang_err at 4+b]
    float*       __restrict__ l2p,      // (NBLK,)
    float*       __restrict__ lpp,      // (NBLK,)
    float*       __restrict__ crp)      // (NBLK,)
{
    __shared__ __align__(16) float sg[BPB * ROWF + 16];   // 2160 + partials
    const int tid  = threadIdx.x;
    const int lane = tid & 63;
    const int wave = tid >> 6;
    const int b0   = blockIdx.x * BPB;
    const int b    = b0 + wave;

    // ---- stage gt_R for 4 b's: 540 float4, fully coalesced (3-step) ----
    const float4* gb4 = (const float4*)(gt_R + (size_t)b0 * ROWF);
    float4* sg4 = (float4*)sg;
    sg4[tid]       = gb4[tid];
    sg4[tid + 256] = gb4[tid + 256];
    if (tid < STG4 - 512) sg4[tid + 512] = gb4[tid + 512];

    // ---- independent register loads (all issued before the barrier) ----
    const int a = lane;
    int lab = label[b];
    float w = -INFINITY;
    float qw = 0, qx = 0, qy = 0, qz = 0;
    float A0=0,A1=0,A2=0,A3=0,A4=0,A5=0,A6=0,A7=0,A8=0;
    if (a < NAc) {
        w = wts[(size_t)b * NAc + a];
        const float* yb = y + (size_t)b * (4 * NAc) + a;
        qw = yb[0 * NAc];
        qx = yb[1 * NAc];
        qy = yb[2 * NAc];
        qz = yb[3 * NAc];
        const float* Ar = anchors + a * 9;       // speculative, L2-hot
        A0 = Ar[0]; A1 = Ar[1]; A2 = Ar[2];
        A3 = Ar[3]; A4 = Ar[4]; A5 = Ar[5];
        A6 = Ar[6]; A7 = Ar[7]; A8 = Ar[8];
    }

    // ---- rotmat (serves both l2 and ang_err) ----
    float n   = sqrtf(qw*qw + qx*qx + qy*qy + qz*qz);
    float inv = 1.0f / fmaxf(n, 1e-8f);
    float pw = qw*inv, px = qx*inv, py = qy*inv, pz = qz*inv;
    float R00 = 1.0f - 2.0f*(py*py + pz*pz);
    float R01 = 2.0f*(px*py - pz*pw);
    float R02 = 2.0f*(px*pz + py*pw);
    float R10 = 2.0f*(px*py + pz*pw);
    float R11 = 1.0f - 2.0f*(px*px + pz*pz);
    float R12 = 2.0f*(py*pz - px*pw);
    float R20 = 2.0f*(px*pz - py*pw);
    float R21 = 2.0f*(py*pz + px*pw);
    float R22 = 1.0f - 2.0f*(px*px + py*py);

    __syncthreads();   // staging complete

    // ---- masked Frobenius term for pair (b, a) ----
    float acc = 0.0f;
    if (a < NAc) {
        const float* g = sg + wave * ROWF + a * 9;   // 2-way bank alias: free
        float g0 = g[0], g1 = g[1], g2 = g[2];
        float g3 = g[3], g4 = g[4], g5 = g[5];
        float g6 = g[6], g7 = g[7], g8 = g[8];
        float xb = 0.5f * (g0 + g4 + g8 - 1.0f);
        if (xb > COS_ONE) {
            float d0 = g0-R00, d1 = g1-R01, d2 = g2-R02;
            float d3 = g3-R10, d4 = g4-R11, d5 = g5-R12;
            float d6 = g6-R20, d7 = g7-R21, d8 = g8-R22;
            acc = d0*d0 + d1*d1 + d2*d2
                + d3*d3 + d4*d4 + d5*d5
                + d6*d6 + d7*d7 + d8*d8;
        }
    }

    // ---- softmax / argmax (first-index tie-break) ----
    float mv = w;
    int   mi = lane;
    for (int off = 32; off; off >>= 1) {
        float ov = __shfl_xor(mv, off, 64);
        int   oi = __shfl_xor(mi, off, 64);
        if (ov > mv || (ov == mv && oi < mi)) { mv = ov; mi = oi; }
    }
    float e  = (a < NAc) ? expf(w - mv) : 0.0f;
    float se = e;
    for (int off = 32; off; off >>= 1) se += __shfl_xor(se, off, 64);
    float lse  = mv + logf(se);
    float wlab = __shfl(w, lab, 64);

    // ---- ang_err: the winning lane already has its rotmat + anchor row ----
    if (lane == mi) {
        float P00 = A0*R00 + A1*R10 + A2*R20;
        float P01 = A0*R01 + A1*R11 + A2*R21;
        float P02 = A0*R02 + A1*R12 + A2*R22;
        float P10 = A3*R00 + A4*R10 + A5*R20;
        float P11 = A3*R01 + A4*R11 + A5*R21;
        float P12 = A3*R02 + A4*R12 + A5*R22;
        float P20 = A6*R00 + A7*R10 + A8*R20;
        float P21 = A6*R01 + A7*R11 + A8*R21;
        float P22 = A6*R02 + A7*R12 + A8*R22;
        const float* tR = sg + wave * ROWF + 29 * 9;   // true_R from LDS
        float tr = P00*tR[0] + P01*tR[1] + P02*tR[2]
                 + P10*tR[3] + P11*tR[4] + P12*tR[5]
                 + P20*tR[6] + P21*tR[7] + P22*tR[8];
        float cx = 0.5f * (tr - 1.0f);
        cx = fminf(fmaxf(cx, -1.0f + 1e-7f), 1.0f - 1e-7f);
        out[4 + b] = acosf(cx);
    }

    // ---- per-wave l2 butterfly, then per-block partials ----
    for (int off = 32; off; off >>= 1) acc += __shfl_xor(acc, off, 64);

    float* s_l2 = sg + BPB * ROWF;       // 4
    float* s_lp = s_l2 + 4;              // 4
    float* s_cr = s_lp + 4;              // 4
    if (lane == 0) {
        s_l2[wave] = acc;
        s_lp[wave] = wlab - lse;
        s_cr[wave] = (mi == lab) ? 1.0f : 0.0f;
    }
    __syncthreads();
    if (tid == 0) {
        l2p[blockIdx.x] = s_l2[0] + s_l2[1] + s_l2[2] + s_l2[3];
        lpp[blockIdx.x] = s_lp[0] + s_lp[1] + s_lp[2] + s_lp[3];
        crp[blockIdx.x] = s_cr[0] + s_cr[1] + s_cr[2] + s_cr[3];
    }
}

// ---------------------------------------------------------------------------
// Finalize: 256 threads, float4 strided loads, per-thread double accumulation,
// deterministic shfl+LDS tree.
// ---------------------------------------------------------------------------
__global__ __launch_bounds__(256) void mtl_final(
    const float* __restrict__ l2p,
    const float* __restrict__ lpp,
    const float* __restrict__ crp,
    float*       __restrict__ out)
{
    const int tid  = threadIdx.x;
    const int lane = tid & 63;
    const int wave = tid >> 6;

    double l2 = 0.0, lp = 0.0, cr = 0.0;
    const float4* l2p4 = (const float4*)l2p;   // 8192/4 = 2048
    const float4* lpp4 = (const float4*)lpp;
    const float4* crp4 = (const float4*)crp;
    for (int i = tid; i < NBLK / 4; i += 256) {
        float4 v = l2p4[i];
        l2 += (double)v.x + (double)v.y + (double)v.z + (double)v.w;
        float4 u = lpp4[i];
        lp += (double)u.x + (double)u.y + (double)u.z + (double)u.w;
        float4 c = crp4[i];
        cr += (double)c.x + (double)c.y + (double)c.z + (double)c.w;
    }

    for (int off = 32; off; off >>= 1) {
        l2 += __shfl_xor(l2, off, 64);
        lp += __shfl_xor(lp, off, 64);
        cr += __shfl_xor(cr, off, 64);
    }
    __shared__ double s_l2[4], s_lp[4], s_cr[4];
    if (lane == 0) { s_l2[wave] = l2; s_lp[wave] = lp; s_cr[wave] = cr; }
    __syncthreads();
    if (tid == 0) {
        double t2 = s_l2[0] + s_l2[1] + s_l2[2] + s_l2[3];
        double tp = s_lp[0] + s_lp[1] + s_lp[2] + s_lp[3];
        double tc = s_cr[0] + s_cr[1] + s_cr[2] + s_cr[3];
        float cls = (float)(-tp / (double)Bc);
        float l2s = (float)(10.0 * t2);      // W_LOSS * l2_loss
        out[0] = cls + l2s;                  // loss
        out[1] = cls;                        // cls_loss
        out[2] = l2s;                        // W_LOSS * l2_loss
        out[3] = (float)(tc / (double)Bc);   // r_acc
    }
}

extern "C" void kernel_launch(void* const* d_in, const int* in_sizes, int n_in,
                              void* d_out, int out_size, void* d_ws, size_t ws_size,
                              hipStream_t stream) {
    const float* wts     = (const float*)d_in[0];
    const int*   label   = (const int*)d_in[1];
    const float* y       = (const float*)d_in[2];
    const float* gt_R    = (const float*)d_in[3];
    const float* anchors = (const float*)d_in[4];
    float* out = (float*)d_out;

    float* l2p = (float*)d_ws;       // NBLK floats
    float* lpp = l2p + NBLK;         // NBLK floats
    float* crp = lpp + NBLK;         // NBLK floats  (96 KB total)

    mtl_all  <<<NBLK, 256, 0, stream>>>(wts, label, y, gt_R, anchors,
                                        out, l2p, lpp, crp);
    mtl_final<<<1, 256, 0, stream>>>(l2p, lpp, crp, out);
}